// Round 13
// baseline (1790.392 us; speedup 1.0000x reference)
//
#include <hip/hip_runtime.h>

#define BT (256*512)   // 131072 positions
#define HID 128
#define EMB 64
#define CH 32          // scan chunk: steps staged per LDS refill

typedef _Float16 half2_t __attribute__((ext_vector_type(2)));

__device__ inline float fast_tanh(float x) {   // 1 - 2/(exp(2x)+1), ~1e-6 abs err
    float e = __expf(2.f * x);
    return 1.f - __fdividef(2.f, e + 1.f);
}

// pin a float4 in VGPRs (compiler cannot rematerialize past this) — R6 recipe
#define OPQ(v) asm volatile("" : "+v"(v.x), "+v"(v.y), "+v"(v.z), "+v"(v.w))
#define W16LOAD \
    float4 w0=wr[0],w1=wr[1],w2=wr[2],w3=wr[3],w4=wr[4],w5=wr[5],w6=wr[6],w7=wr[7], \
           w8=wr[8],w9=wr[9],w10=wr[10],w11=wr[11],w12=wr[12],w13=wr[13],w14=wr[14],w15=wr[15];
#define W16PIN \
    OPQ(w0);OPQ(w1);OPQ(w2);OPQ(w3);OPQ(w4);OPQ(w5);OPQ(w6);OPQ(w7); \
    OPQ(w8);OPQ(w9);OPQ(w10);OPQ(w11);OPQ(w12);OPQ(w13);OPQ(w14);OPQ(w15);
#define W32LOAD W16LOAD \
    float4 w16=wr[16],w17=wr[17],w18=wr[18],w19=wr[19],w20=wr[20],w21=wr[21],w22=wr[22],w23=wr[23], \
           w24=wr[24],w25=wr[25],w26=wr[26],w27=wr[27],w28=wr[28],w29=wr[29],w30=wr[30],w31=wr[31];
#define W32PIN W16PIN \
    OPQ(w16);OPQ(w17);OPQ(w18);OPQ(w19);OPQ(w20);OPQ(w21);OPQ(w22);OPQ(w23); \
    OPQ(w24);OPQ(w25);OPQ(w26);OPQ(w27);OPQ(w28);OPQ(w29);OPQ(w30);OPQ(w31);

// fp32 dot: 32 float4 h reads × pinned weight float4s
#define ACC4(n) { float4 hv = hp[n]; \
    a0 = fmaf(hv.x, w##n.x, a0); a1 = fmaf(hv.y, w##n.y, a1); \
    a2 = fmaf(hv.z, w##n.z, a2); a3 = fmaf(hv.w, w##n.w, a3); }
#define ACC16 ACC4(0)ACC4(1)ACC4(2)ACC4(3)ACC4(4)ACC4(5)ACC4(6)ACC4(7) \
              ACC4(8)ACC4(9)ACC4(10)ACC4(11)ACC4(12)ACC4(13)ACC4(14)ACC4(15)
#define ACC32 ACC16 \
              ACC4(16)ACC4(17)ACC4(18)ACC4(19)ACC4(20)ACC4(21)ACC4(22)ACC4(23) \
              ACC4(24)ACC4(25)ACC4(26)ACC4(27)ACC4(28)ACC4(29)ACC4(30)ACC4(31)

// fp16-pair h × fp32 weights (feed-forward path only)
#define BCH(u) __builtin_bit_cast(half2_t, u)
#define FMX(q, wa, wb) { \
    half2_t p0=BCH(q.x), p1=BCH(q.y), p2=BCH(q.z), p3=BCH(q.w); \
    a0 = fmaf((float)p0.x, wa.x, a0); a1 = fmaf((float)p0.y, wa.y, a1); \
    a2 = fmaf((float)p1.x, wa.z, a2); a3 = fmaf((float)p1.y, wa.w, a3); \
    a0 = fmaf((float)p2.x, wb.x, a0); a1 = fmaf((float)p2.y, wb.y, a1); \
    a2 = fmaf((float)p3.x, wb.z, a2); a3 = fmaf((float)p3.y, wb.w, a3); }
// full 128-value fp16 dot, in two halves to limit live temps
#define DOT128H(hsrc) \
    { uint4 q0=hsrc[0],q1=hsrc[1],q2=hsrc[2],q3=hsrc[3], \
            q4=hsrc[4],q5=hsrc[5],q6=hsrc[6],q7=hsrc[7]; \
      FMX(q0,w0,w1) FMX(q1,w2,w3) FMX(q2,w4,w5) FMX(q3,w6,w7) \
      FMX(q4,w8,w9) FMX(q5,w10,w11) FMX(q6,w12,w13) FMX(q7,w14,w15) } \
    { uint4 q0=hsrc[8],q1=hsrc[9],q2=hsrc[10],q3=hsrc[11], \
            q4=hsrc[12],q5=hsrc[13],q6=hsrc[14],q7=hsrc[15]; \
      FMX(q0,w16,w17) FMX(q1,w18,w19) FMX(q2,w20,w21) FMX(q3,w22,w23) \
      FMX(q4,w24,w25) FMX(q5,w26,w27) FMX(q6,w28,w29) FMX(q7,w30,w31) }

// ---------------- kernel 1: embedding gather + layer-1 input GEMM (R10 form)
__global__ __launch_bounds__(256) void k_embed_pre1(
    const int* __restrict__ x, const float* __restrict__ emb,
    const float* __restrict__ Wih1, const float* __restrict__ bih1,
    const float* __restrict__ bhh1, float* __restrict__ pre1)
{
    __shared__ float sA[32][128];
    __shared__ float sW[32][132];
    __shared__ int stok[128];
    const int tid = threadIdx.x;
    const int base = blockIdx.x * 128;
    const int tx = tid & 15, ty = tid >> 4;
    const int ox = tx * 8, py = ty * 8;
    const int pl = tid & 127, half = tid >> 7;
    if (tid < 128) stok[tid] = x[base + tid];
    float acc[8][8];
#pragma unroll
    for (int p = 0; p < 8; ++p)
#pragma unroll
        for (int o = 0; o < 8; ++o) acc[p][o] = 0.f;
    __syncthreads();
    for (int kc = 0; kc < 2; ++kc) {            // K = 64
        {
            const float4* ws = (const float4*)(Wih1 + (size_t)pl * EMB + kc * 32 + half * 16);
            float4 q0 = ws[0], q1 = ws[1], q2 = ws[2], q3 = ws[3];
            const float4* as = (const float4*)(emb + (size_t)stok[pl] * EMB + kc * 32 + half * 16);
            float4 e0 = as[0], e1 = as[1], e2 = as[2], e3 = as[3];
            const int jb = half * 16;
            sW[jb+ 0][pl]=q0.x; sW[jb+ 1][pl]=q0.y; sW[jb+ 2][pl]=q0.z; sW[jb+ 3][pl]=q0.w;
            sW[jb+ 4][pl]=q1.x; sW[jb+ 5][pl]=q1.y; sW[jb+ 6][pl]=q1.z; sW[jb+ 7][pl]=q1.w;
            sW[jb+ 8][pl]=q2.x; sW[jb+ 9][pl]=q2.y; sW[jb+10][pl]=q2.z; sW[jb+11][pl]=q2.w;
            sW[jb+12][pl]=q3.x; sW[jb+13][pl]=q3.y; sW[jb+14][pl]=q3.z; sW[jb+15][pl]=q3.w;
            sA[jb+ 0][pl]=e0.x; sA[jb+ 1][pl]=e0.y; sA[jb+ 2][pl]=e0.z; sA[jb+ 3][pl]=e0.w;
            sA[jb+ 4][pl]=e1.x; sA[jb+ 5][pl]=e1.y; sA[jb+ 6][pl]=e1.z; sA[jb+ 7][pl]=e1.w;
            sA[jb+ 8][pl]=e2.x; sA[jb+ 9][pl]=e2.y; sA[jb+10][pl]=e2.z; sA[jb+11][pl]=e2.w;
            sA[jb+12][pl]=e3.x; sA[jb+13][pl]=e3.y; sA[jb+14][pl]=e3.z; sA[jb+15][pl]=e3.w;
        }
        __syncthreads();
#pragma unroll 4
        for (int j = 0; j < 32; ++j) {
            float4 a0 = *(const float4*)&sA[j][py];
            float4 a1 = *(const float4*)&sA[j][py + 4];
            float4 b0 = *(const float4*)&sW[j][ox];
            float4 b1 = *(const float4*)&sW[j][ox + 4];
            float av[8] = {a0.x,a0.y,a0.z,a0.w,a1.x,a1.y,a1.z,a1.w};
            float bv[8] = {b0.x,b0.y,b0.z,b0.w,b1.x,b1.y,b1.z,b1.w};
#pragma unroll
            for (int p = 0; p < 8; ++p)
#pragma unroll
                for (int o = 0; o < 8; ++o)
                    acc[p][o] = fmaf(av[p], bv[o], acc[p][o]);
        }
        __syncthreads();
    }
    float bo[8];
#pragma unroll
    for (int o = 0; o < 8; ++o) bo[o] = bih1[ox + o] + bhh1[ox + o];
#pragma unroll
    for (int p = 0; p < 8; ++p) {
        float* cp = pre1 + (size_t)(base + py + p) * HID + ox;
        *(float4*)cp       = make_float4(acc[p][0]+bo[0], acc[p][1]+bo[1], acc[p][2]+bo[2], acc[p][3]+bo[3]);
        *(float4*)(cp + 4) = make_float4(acc[p][4]+bo[4], acc[p][5]+bo[5], acc[p][6]+bo[6], acc[p][7]+bo[7]);
    }
}

// block-wide sum for 384 threads (6 waves); pass 0 from non-contributing lanes
__device__ inline float bsum384(float v, volatile float* sc, int tid) {
#pragma unroll
    for (int off = 32; off > 0; off >>= 1) v += __shfl_down(v, off, 64);
    __syncthreads();
    if ((tid & 63) == 0) sc[tid >> 6] = v;
    __syncthreads();
    float s = 0.f;
#pragma unroll
    for (int k = 0; k < 6; ++k) s += sc[k];
    return s;
}

// ---------------- kernel 2: FUSED two-layer recurrence, 2-step skew, ONE
// barrier per step. 384 threads (6 waves), full weight row per thread
// (32 pinned float4; waves_per_eu(1,2) -> 256-VGPR budget so pins stay in
// arch VGPRs, no AGPR shuffle — R12's VGPR=68 pathology).
//   A (tid 0-127):   h1_t    = tanh(pre_t + Whh1@h1_{t-1})      [fp32 reads]
//   B (tid 128-255): q_{t-1} = bias2 + Wih2@h1_{t-1}            [fp16 reads, FF path]
//   C (tid 256-383): h2_{t-2}= tanh(q_{t-2} + Whh2@h2_{t-3})    [fp32 reads]
// Double-buffered rings (write slot (t+1)&1, read slot t&1) make one barrier
// sufficient. Two drain iterations finish h2_511.
__global__ __launch_bounds__(384)
__attribute__((amdgpu_waves_per_eu(1, 2)))
void k_rnn_fused(
    const float* __restrict__ pre1, const float* __restrict__ Whh1,
    const float* __restrict__ Wih2, const float* __restrict__ bih2,
    const float* __restrict__ bhh2, const float* __restrict__ Whh2,
    const float* __restrict__ ln_g, const float* __restrict__ ln_b,
    const float* __restrict__ projW, const float* __restrict__ proj_b,
    const float* __restrict__ on_g, const float* __restrict__ on_b,
    float* __restrict__ out)
{
    __shared__ __align__(16) float    h1b[2][HID];   // fp32 h1 ring (A reads)
    __shared__ __align__(16) _Float16 h1h[2][HID];   // fp16 h1 ring (B reads)
    __shared__ __align__(16) float    h2b[2][HID];   // fp32 h2 ring (C reads)
    __shared__ __align__(16) float    sq[2][HID];    // q ring (B writes, C reads)
    __shared__ __align__(16) float spre[CH * HID];   // staged pre1 rows (16 KB)
    __shared__ float sfin[HID];
    __shared__ float srep[HID];
    __shared__ float sc[6];
    const int b   = blockIdx.x;
    const int tid = threadIdx.x;
    const int g   = tid >> 7;         // 0=A, 1=B, 2=C (2 waves each, uniform)
    const int i   = tid & 127;
    const float* wbase = (g == 0) ? Whh1 : ((g == 1) ? Wih2 : Whh2);
    const float4* wr = reinterpret_cast<const float4*>(wbase + (size_t)i * HID);
    W32LOAD; W32PIN;
    const float bias2 = (g == 1) ? (bih2[i] + bhh2[i]) : 0.f;
    if (tid < 128) {
        h1b[0][i] = 0.f; h1h[0][i] = (_Float16)0.f; h2b[0][i] = 0.f;
        sq[0][i] = 0.f;  sq[1][i] = 0.f;
    }
    const float4* gsrc = reinterpret_cast<const float4*>(pre1 + (size_t)b * 512 * HID);
    float4*       spv  = reinterpret_cast<float4*>(spre);
    __syncthreads();
    for (int c = 0; c < 512 / CH; ++c) {
        // stage CH pre1 rows: 1024 float4 by 384 threads (2 or 3 each)
        float4 r0 = gsrc[c * 1024 + tid];
        float4 r1 = gsrc[c * 1024 + tid + 384];
        float4 r2;
        if (tid < 256) r2 = gsrc[c * 1024 + tid + 768];
        spv[tid]       = r0;
        spv[tid + 384] = r1;
        if (tid < 256) spv[tid + 768] = r2;
        __syncthreads();
        for (int s = 0; s < CH; ++s) {
            const int t = c * CH + s;
            float val;
            if (g == 0) {
                const float4* hp = reinterpret_cast<const float4*>(h1b[t & 1]);
                float a0 = 0, a1 = 0, a2 = 0, a3 = 0;
                ACC32;
                val = fast_tanh(spre[s * HID + i] + ((a0 + a1) + (a2 + a3)));
                h1b[(t + 1) & 1][i] = val;
                h1h[(t + 1) & 1][i] = (_Float16)val;
            } else if (g == 1) {
                const uint4* hsrc = reinterpret_cast<const uint4*>(h1h[t & 1]);
                float a0 = 0, a1 = 0, a2 = 0, a3 = 0;
                DOT128H(hsrc);
                val = bias2 + ((a0 + a1) + (a2 + a3));
                sq[(t + 1) & 1][i] = val;
            } else {
                const float4* hp = reinterpret_cast<const float4*>(h2b[t & 1]);
                float a0 = 0, a1 = 0, a2 = 0, a3 = 0;
                ACC32;
                float qv = sq[t & 1][i];
                val = (t >= 2) ? fast_tanh(qv + ((a0 + a1) + (a2 + a3))) : 0.f;
                h2b[(t + 1) & 1][i] = val;
            }
            __syncthreads();           // the ONLY barrier per step
        }
    }
    // drain t=512: B -> q_511 (sq[1]); C -> h2_510 (h2b[1])
    if (g == 1) {
        const uint4* hsrc = reinterpret_cast<const uint4*>(h1h[0]);
        float a0 = 0, a1 = 0, a2 = 0, a3 = 0;
        DOT128H(hsrc);
        sq[1][i] = bias2 + ((a0 + a1) + (a2 + a3));
    } else if (g == 2) {
        const float4* hp = reinterpret_cast<const float4*>(h2b[0]);
        float a0 = 0, a1 = 0, a2 = 0, a3 = 0;
        ACC32;
        h2b[1][i] = fast_tanh(sq[0][i] + ((a0 + a1) + (a2 + a3)));
    }
    __syncthreads();
    // drain t=513: C -> h2_511 -> sfin
    if (g == 2) {
        const float4* hp = reinterpret_cast<const float4*>(h2b[1]);
        float a0 = 0, a1 = 0, a2 = 0, a3 = 0;
        ACC32;
        sfin[i] = fast_tanh(sq[1][i] + ((a0 + a1) + (a2 + a3)));
    }
    __syncthreads();
    // ---- epilogue: LN -> proj+tanh -> LN (values on tid<128; all barrier)
    float hn = (tid < 128) ? sfin[i] : 0.f;
    float s1 = bsum384(hn, sc, tid);
    float s2 = bsum384(hn * hn, sc, tid);
    float mu = s1 * (1.f / 128.f);
    float var = s2 * (1.f / 128.f) - mu * mu;
    __syncthreads();
    if (tid < 128) srep[i] = (hn - mu) * rsqrtf(var + 1e-5f) * ln_g[i] + ln_b[i];
    __syncthreads();
    float pv = 0.f;
    if (tid < 128) {
        float a0 = proj_b[i], a1 = 0, a2 = 0, a3 = 0;
        const float4* hp = reinterpret_cast<const float4*>(srep);
        const float4* pr = reinterpret_cast<const float4*>(projW + (size_t)i * HID);
#pragma unroll
        for (int k = 0; k < HID / 4; ++k) {
            float4 u = pr[k];
            float4 hv = hp[k];
            a0 = fmaf(hv.x, u.x, a0); a1 = fmaf(hv.y, u.y, a1);
            a2 = fmaf(hv.z, u.z, a2); a3 = fmaf(hv.w, u.w, a3);
        }
        pv = tanhf((a0 + a1) + (a2 + a3));
    }
    float t1 = bsum384(pv, sc, tid);
    float t2 = bsum384(pv * pv, sc, tid);
    float mu2 = t1 * (1.f / 128.f);
    float var2 = t2 * (1.f / 128.f) - mu2 * mu2;
    if (tid < 128)
        out[(size_t)b * HID + i] = (pv - mu2) * rsqrtf(var2 + 1e-5f) * on_g[i] + on_b[i];
}

extern "C" void kernel_launch(void* const* d_in, const int* in_sizes, int n_in,
                              void* d_out, int out_size, void* d_ws, size_t ws_size,
                              hipStream_t stream)
{
    const int*   x     = (const int*)  d_in[0];
    const float* emb   = (const float*)d_in[1];
    const float* Wih1  = (const float*)d_in[2];
    const float* bih1  = (const float*)d_in[3];
    const float* Whh1  = (const float*)d_in[4];
    const float* bhh1  = (const float*)d_in[5];
    const float* Wih2  = (const float*)d_in[6];
    const float* bih2  = (const float*)d_in[7];
    const float* Whh2  = (const float*)d_in[8];
    const float* bhh2  = (const float*)d_in[9];
    const float* ln_g  = (const float*)d_in[10];
    const float* ln_b  = (const float*)d_in[11];
    const float* projW = (const float*)d_in[12];
    const float* projb = (const float*)d_in[13];
    const float* on_g  = (const float*)d_in[14];
    const float* on_b  = (const float*)d_in[15];

    float* pre1 = (float*)d_ws;   // 64 MiB fp32

    k_embed_pre1<<<BT / 128, 256, 0, stream>>>(x, emb, Wih1, bih1, bhh1, pre1);
    k_rnn_fused<<<256, 384, 0, stream>>>(pre1, Whh1, Wih2, bih2, bhh2, Whh2,
                                         ln_g, ln_b, projW, projb, on_g, on_b,
                                         (float*)d_out);
}

// Round 14
// 596.943 us; speedup vs baseline: 2.9993x; 2.9993x over previous
//
#include <hip/hip_runtime.h>

#define BT (256*512)   // 131072 positions
#define HID 128
#define EMB 64
#define CH 32          // scan chunk: steps staged per LDS refill

typedef _Float16 half2_t __attribute__((ext_vector_type(2)));

__device__ inline float fast_tanh(float x) {   // 1 - 2/(exp(2x)+1), ~1e-6 abs err
    float e = __expf(2.f * x);
    return 1.f - __fdividef(2.f, e + 1.f);
}

// pin a float4 in VGPRs (compiler cannot rematerialize past this) — R6 recipe
#define OPQ(v) asm volatile("" : "+v"(v.x), "+v"(v.y), "+v"(v.z), "+v"(v.w))
#define W16LOAD \
    float4 w0=wr[0],w1=wr[1],w2=wr[2],w3=wr[3],w4=wr[4],w5=wr[5],w6=wr[6],w7=wr[7], \
           w8=wr[8],w9=wr[9],w10=wr[10],w11=wr[11],w12=wr[12],w13=wr[13],w14=wr[14],w15=wr[15];
#define W16PIN \
    OPQ(w0);OPQ(w1);OPQ(w2);OPQ(w3);OPQ(w4);OPQ(w5);OPQ(w6);OPQ(w7); \
    OPQ(w8);OPQ(w9);OPQ(w10);OPQ(w11);OPQ(w12);OPQ(w13);OPQ(w14);OPQ(w15);

// fp32 dot over 64 values: 16 float4 LDS reads (2 broadcast addrs/wave = free)
#define ACC4(n) { float4 hv = hp[n]; \
    a0 = fmaf(hv.x, w##n.x, a0); a1 = fmaf(hv.y, w##n.y, a1); \
    a2 = fmaf(hv.z, w##n.z, a2); a3 = fmaf(hv.w, w##n.w, a3); }
#define ACC16 ACC4(0)ACC4(1)ACC4(2)ACC4(3)ACC4(4)ACC4(5)ACC4(6)ACC4(7) \
              ACC4(8)ACC4(9)ACC4(10)ACC4(11)ACC4(12)ACC4(13)ACC4(14)ACC4(15)

// fp16-pair h × fp32 weights (feed-forward path only): 8 uint4 = 64 values
#define BCH(u) __builtin_bit_cast(half2_t, u)
#define FMX(q, wa, wb) { \
    half2_t p0=BCH(q.x), p1=BCH(q.y), p2=BCH(q.z), p3=BCH(q.w); \
    a0 = fmaf((float)p0.x, wa.x, a0); a1 = fmaf((float)p0.y, wa.y, a1); \
    a2 = fmaf((float)p1.x, wa.z, a2); a3 = fmaf((float)p1.y, wa.w, a3); \
    a0 = fmaf((float)p2.x, wb.x, a0); a1 = fmaf((float)p2.y, wb.y, a1); \
    a2 = fmaf((float)p3.x, wb.z, a2); a3 = fmaf((float)p3.y, wb.w, a3); }
#define DOT64H(hsrc) \
    uint4 q0=hsrc[0],q1=hsrc[1],q2=hsrc[2],q3=hsrc[3], \
          q4=hsrc[4],q5=hsrc[5],q6=hsrc[6],q7=hsrc[7]; \
    FMX(q0,w0,w1) FMX(q1,w2,w3) FMX(q2,w4,w5) FMX(q3,w6,w7) \
    FMX(q4,w8,w9) FMX(q5,w10,w11) FMX(q6,w12,w13) FMX(q7,w14,w15)

// ---------------- kernel 1: embedding gather + layer-1 input GEMM (R10 form)
__global__ __launch_bounds__(256) void k_embed_pre1(
    const int* __restrict__ x, const float* __restrict__ emb,
    const float* __restrict__ Wih1, const float* __restrict__ bih1,
    const float* __restrict__ bhh1, float* __restrict__ pre1)
{
    __shared__ float sA[32][128];
    __shared__ float sW[32][132];
    __shared__ int stok[128];
    const int tid = threadIdx.x;
    const int base = blockIdx.x * 128;
    const int tx = tid & 15, ty = tid >> 4;
    const int ox = tx * 8, py = ty * 8;
    const int pl = tid & 127, half = tid >> 7;
    if (tid < 128) stok[tid] = x[base + tid];
    float acc[8][8];
#pragma unroll
    for (int p = 0; p < 8; ++p)
#pragma unroll
        for (int o = 0; o < 8; ++o) acc[p][o] = 0.f;
    __syncthreads();
    for (int kc = 0; kc < 2; ++kc) {            // K = 64
        {
            const float4* ws = (const float4*)(Wih1 + (size_t)pl * EMB + kc * 32 + half * 16);
            float4 q0 = ws[0], q1 = ws[1], q2 = ws[2], q3 = ws[3];
            const float4* as = (const float4*)(emb + (size_t)stok[pl] * EMB + kc * 32 + half * 16);
            float4 e0 = as[0], e1 = as[1], e2 = as[2], e3 = as[3];
            const int jb = half * 16;
            sW[jb+ 0][pl]=q0.x; sW[jb+ 1][pl]=q0.y; sW[jb+ 2][pl]=q0.z; sW[jb+ 3][pl]=q0.w;
            sW[jb+ 4][pl]=q1.x; sW[jb+ 5][pl]=q1.y; sW[jb+ 6][pl]=q1.z; sW[jb+ 7][pl]=q1.w;
            sW[jb+ 8][pl]=q2.x; sW[jb+ 9][pl]=q2.y; sW[jb+10][pl]=q2.z; sW[jb+11][pl]=q2.w;
            sW[jb+12][pl]=q3.x; sW[jb+13][pl]=q3.y; sW[jb+14][pl]=q3.z; sW[jb+15][pl]=q3.w;
            sA[jb+ 0][pl]=e0.x; sA[jb+ 1][pl]=e0.y; sA[jb+ 2][pl]=e0.z; sA[jb+ 3][pl]=e0.w;
            sA[jb+ 4][pl]=e1.x; sA[jb+ 5][pl]=e1.y; sA[jb+ 6][pl]=e1.z; sA[jb+ 7][pl]=e1.w;
            sA[jb+ 8][pl]=e2.x; sA[jb+ 9][pl]=e2.y; sA[jb+10][pl]=e2.z; sA[jb+11][pl]=e2.w;
            sA[jb+12][pl]=e3.x; sA[jb+13][pl]=e3.y; sA[jb+14][pl]=e3.z; sA[jb+15][pl]=e3.w;
        }
        __syncthreads();
#pragma unroll 4
        for (int j = 0; j < 32; ++j) {
            float4 a0 = *(const float4*)&sA[j][py];
            float4 a1 = *(const float4*)&sA[j][py + 4];
            float4 b0 = *(const float4*)&sW[j][ox];
            float4 b1 = *(const float4*)&sW[j][ox + 4];
            float av[8] = {a0.x,a0.y,a0.z,a0.w,a1.x,a1.y,a1.z,a1.w};
            float bv[8] = {b0.x,b0.y,b0.z,b0.w,b1.x,b1.y,b1.z,b1.w};
#pragma unroll
            for (int p = 0; p < 8; ++p)
#pragma unroll
                for (int o = 0; o < 8; ++o)
                    acc[p][o] = fmaf(av[p], bv[o], acc[p][o]);
        }
        __syncthreads();
    }
    float bo[8];
#pragma unroll
    for (int o = 0; o < 8; ++o) bo[o] = bih1[ox + o] + bhh1[ox + o];
#pragma unroll
    for (int p = 0; p < 8; ++p) {
        float* cp = pre1 + (size_t)(base + py + p) * HID + ox;
        *(float4*)cp       = make_float4(acc[p][0]+bo[0], acc[p][1]+bo[1], acc[p][2]+bo[2], acc[p][3]+bo[3]);
        *(float4*)(cp + 4) = make_float4(acc[p][4]+bo[4], acc[p][5]+bo[5], acc[p][6]+bo[6], acc[p][7]+bo[7]);
    }
}

// block-wide sum for 768 threads (12 waves); pass 0 from non-contributing lanes
__device__ inline float bsum768(float v, volatile float* sc, int tid) {
#pragma unroll
    for (int off = 32; off > 0; off >>= 1) v += __shfl_down(v, off, 64);
    __syncthreads();
    if ((tid & 63) == 0) sc[tid >> 6] = v;
    __syncthreads();
    float s = 0.f;
#pragma unroll
    for (int k = 0; k < 12; ++k) s += sc[k];
    return s;
}

// ---------------- kernel 2: FUSED two-layer recurrence, 2-step skew, ONE
// barrier per step, IN-WAVE K-split combine.
// 768 threads, 12 waves, 3 groups of 4 waves. Within a group-wave: lane l<32
// handles K[0:64) of row wv*32+l, lane l>=32 handles K[64:128) of the same
// row; combine = one shfl_xor(32) — no sp LDS round-trip, no 2nd barrier.
// 64 pinned floats/thread (R12-proven allocation: no scratch spill).
//   A (g=0): h1_t    = tanh(pre_t + Whh1@h1_{t-1})   [fp32 reads]
//   B (g=1): q_{t-1} = bias2 + Wih2@h1_{t-1}         [fp16 reads, FF path]
//   C (g=2): h2_{t-2}= tanh(q_{t-2} + Whh2@h2_{t-3}) [fp32 reads; R13 skew]
__global__ __launch_bounds__(768)
__attribute__((amdgpu_waves_per_eu(1, 3)))
void k_rnn_fused(
    const float* __restrict__ pre1, const float* __restrict__ Whh1,
    const float* __restrict__ Wih2, const float* __restrict__ bih2,
    const float* __restrict__ bhh2, const float* __restrict__ Whh2,
    const float* __restrict__ ln_g, const float* __restrict__ ln_b,
    const float* __restrict__ projW, const float* __restrict__ proj_b,
    const float* __restrict__ on_g, const float* __restrict__ on_b,
    float* __restrict__ out)
{
    __shared__ __align__(16) float    h1b[2][HID];   // fp32 h1 ring (A reads)
    __shared__ __align__(16) _Float16 h1h[2][HID];   // fp16 h1 ring (B reads)
    __shared__ __align__(16) float    h2b[2][HID];   // fp32 h2 ring (C reads)
    __shared__ __align__(16) float    sq[2][HID];    // q ring (B writes, C reads)
    __shared__ __align__(16) float spre[CH * HID];   // staged pre1 rows (16 KB)
    __shared__ float sfin[HID];
    __shared__ float sc[12];
    const int b    = blockIdx.x;
    const int tid  = threadIdx.x;
    const int g    = tid >> 8;            // 0=A, 1=B, 2=C (4 waves each)
    const int gt   = tid & 255;
    const int lane = gt & 63;
    const int row  = (gt >> 6) * 32 + (lane & 31);
    const int kh   = lane >> 5;           // K-half within the wave
    const float* wbase = (g == 0) ? Whh1 : ((g == 1) ? Wih2 : Whh2);
    const float4* wr = reinterpret_cast<const float4*>(wbase + (size_t)row * HID + kh * 64);
    W16LOAD; W16PIN;
    const float bias2 = (g == 1) ? (bih2[row] + bhh2[row]) : 0.f;
    if (tid < 128) {
        h1b[0][tid] = 0.f; h1h[0][tid] = (_Float16)0.f; h2b[0][tid] = 0.f;
        sq[0][tid] = 0.f;  sq[1][tid] = 0.f;
    }
    const float4* gsrc = reinterpret_cast<const float4*>(pre1 + (size_t)b * 512 * HID);
    float4*       spv  = reinterpret_cast<float4*>(spre);
    __syncthreads();
    for (int c = 0; c < 512 / CH; ++c) {
        // stage CH pre1 rows: 1024 float4, threads 0..511 take 2 each
        if (tid < 512) {
            float4 r0 = gsrc[c * 1024 + tid];
            float4 r1 = gsrc[c * 1024 + tid + 512];
            spv[tid]       = r0;
            spv[tid + 512] = r1;
        }
        __syncthreads();
        for (int s = 0; s < CH; ++s) {
            const int t = c * CH + s;
            float v;
            if (g == 0) {
                const float4* hp = reinterpret_cast<const float4*>(h1b[t & 1] + kh * 64);
                float a0 = 0, a1 = 0, a2 = 0, a3 = 0;
                ACC16;
                v = (a0 + a1) + (a2 + a3);
            } else if (g == 1) {
                const uint4* hsrc = reinterpret_cast<const uint4*>(h1h[t & 1] + kh * 64);
                float a0 = 0, a1 = 0, a2 = 0, a3 = 0;
                DOT64H(hsrc);
                v = (a0 + a1) + (a2 + a3);
            } else {
                const float4* hp = reinterpret_cast<const float4*>(h2b[t & 1] + kh * 64);
                float a0 = 0, a1 = 0, a2 = 0, a3 = 0;
                ACC16;
                v = (a0 + a1) + (a2 + a3);
            }
            v += __shfl_xor(v, 32, 64);           // in-wave K-combine
            if (lane < 32) {
                if (g == 0) {
                    float hn = fast_tanh(spre[s * HID + row] + v);
                    h1b[(t + 1) & 1][row] = hn;
                    h1h[(t + 1) & 1][row] = (_Float16)hn;
                } else if (g == 1) {
                    sq[(t + 1) & 1][row] = bias2 + v;
                } else {
                    float val = (t >= 2) ? fast_tanh(sq[t & 1][row] + v) : 0.f;
                    h2b[(t + 1) & 1][row] = val;
                }
            }
            __syncthreads();                      // the ONLY barrier per step
        }
    }
    // drain t=512: B -> q_511 (sq[1]); C -> h2_510 (h2b[1])
    {
        float v = 0.f;
        if (g == 1) {
            const uint4* hsrc = reinterpret_cast<const uint4*>(h1h[0] + kh * 64);
            float a0 = 0, a1 = 0, a2 = 0, a3 = 0;
            DOT64H(hsrc);
            v = (a0 + a1) + (a2 + a3);
        } else if (g == 2) {
            const float4* hp = reinterpret_cast<const float4*>(h2b[0] + kh * 64);
            float a0 = 0, a1 = 0, a2 = 0, a3 = 0;
            ACC16;
            v = (a0 + a1) + (a2 + a3);
        }
        v += __shfl_xor(v, 32, 64);
        if (lane < 32) {
            if (g == 1)      sq[1][row]  = bias2 + v;
            else if (g == 2) h2b[1][row] = fast_tanh(sq[0][row] + v);
        }
    }
    __syncthreads();
    // drain t=513: C -> h2_511 -> sfin
    if (g == 2) {
        const float4* hp = reinterpret_cast<const float4*>(h2b[1] + kh * 64);
        float a0 = 0, a1 = 0, a2 = 0, a3 = 0;
        ACC16;
        float v = (a0 + a1) + (a2 + a3);
        v += __shfl_xor(v, 32, 64);
        if (lane < 32) sfin[row] = fast_tanh(sq[1][row] + v);
    }
    __syncthreads();
    // ---- epilogue: LN -> proj+tanh -> LN (values on tid<128; all barrier)
    const int ei = tid & 127;
    float hn = (tid < 128) ? sfin[ei] : 0.f;
    float s1 = bsum768(hn, sc, tid);
    float s2 = bsum768(hn * hn, sc, tid);
    float mu = s1 * (1.f / 128.f);
    float var = s2 * (1.f / 128.f) - mu * mu;
    __syncthreads();
    if (tid < 128) spre[ei] = (hn - mu) * rsqrtf(var + 1e-5f) * ln_g[ei] + ln_b[ei];
    __syncthreads();
    float pv = 0.f;
    if (tid < 128) {
        float a0 = proj_b[ei], a1 = 0, a2 = 0, a3 = 0;
        const float4* hp = reinterpret_cast<const float4*>(spre);
        const float4* pr = reinterpret_cast<const float4*>(projW + (size_t)ei * HID);
#pragma unroll
        for (int k = 0; k < HID / 4; ++k) {
            float4 u = pr[k];
            float4 hv = hp[k];
            a0 = fmaf(hv.x, u.x, a0); a1 = fmaf(hv.y, u.y, a1);
            a2 = fmaf(hv.z, u.z, a2); a3 = fmaf(hv.w, u.w, a3);
        }
        pv = tanhf((a0 + a1) + (a2 + a3));
    }
    float t1 = bsum768(pv, sc, tid);
    float t2 = bsum768(pv * pv, sc, tid);
    float mu2 = t1 * (1.f / 128.f);
    float var2 = t2 * (1.f / 128.f) - mu2 * mu2;
    if (tid < 128)
        out[(size_t)b * HID + ei] = (pv - mu2) * rsqrtf(var2 + 1e-5f) * on_g[ei] + on_b[ei];
}

extern "C" void kernel_launch(void* const* d_in, const int* in_sizes, int n_in,
                              void* d_out, int out_size, void* d_ws, size_t ws_size,
                              hipStream_t stream)
{
    const int*   x     = (const int*)  d_in[0];
    const float* emb   = (const float*)d_in[1];
    const float* Wih1  = (const float*)d_in[2];
    const float* bih1  = (const float*)d_in[3];
    const float* Whh1  = (const float*)d_in[4];
    const float* bhh1  = (const float*)d_in[5];
    const float* Wih2  = (const float*)d_in[6];
    const float* bih2  = (const float*)d_in[7];
    const float* Whh2  = (const float*)d_in[8];
    const float* bhh2  = (const float*)d_in[9];
    const float* ln_g  = (const float*)d_in[10];
    const float* ln_b  = (const float*)d_in[11];
    const float* projW = (const float*)d_in[12];
    const float* projb = (const float*)d_in[13];
    const float* on_g  = (const float*)d_in[14];
    const float* on_b  = (const float*)d_in[15];

    float* pre1 = (float*)d_ws;   // 64 MiB fp32

    k_embed_pre1<<<BT / 128, 256, 0, stream>>>(x, emb, Wih1, bih1, bhh1, pre1);
    k_rnn_fused<<<256, 768, 0, stream>>>(pre1, Whh1, Wih2, bih2, bhh2, Whh2,
                                         ln_g, ln_b, projW, projb, on_g, on_b,
                                         (float*)d_out);
}

// Round 15
// 567.547 us; speedup vs baseline: 3.1546x; 1.0518x over previous
//
#include <hip/hip_runtime.h>

#define BT (256*512)   // 131072 positions
#define HID 128
#define EMB 64
#define CH 32          // scan chunk: steps staged per LDS refill

typedef _Float16 half2_t __attribute__((ext_vector_type(2)));

__device__ inline float fast_tanh(float x) {   // 1 - 2/(exp(2x)+1), ~1e-6 abs err
    float e = __expf(2.f * x);
    return 1.f - __fdividef(2.f, e + 1.f);
}

// pin a float4 in VGPRs (compiler cannot rematerialize past this) — R6 recipe
#define OPQ(v) asm volatile("" : "+v"(v.x), "+v"(v.y), "+v"(v.z), "+v"(v.w))
#define W16LOAD \
    float4 w0=wr[0],w1=wr[1],w2=wr[2],w3=wr[3],w4=wr[4],w5=wr[5],w6=wr[6],w7=wr[7], \
           w8=wr[8],w9=wr[9],w10=wr[10],w11=wr[11],w12=wr[12],w13=wr[13],w14=wr[14],w15=wr[15];
#define W16PIN \
    OPQ(w0);OPQ(w1);OPQ(w2);OPQ(w3);OPQ(w4);OPQ(w5);OPQ(w6);OPQ(w7); \
    OPQ(w8);OPQ(w9);OPQ(w10);OPQ(w11);OPQ(w12);OPQ(w13);OPQ(w14);OPQ(w15);

// fp32 dot over 64 values: 16 float4 LDS reads
#define ACC4(n) { float4 hv = hp[n]; \
    a0 = fmaf(hv.x, w##n.x, a0); a1 = fmaf(hv.y, w##n.y, a1); \
    a2 = fmaf(hv.z, w##n.z, a2); a3 = fmaf(hv.w, w##n.w, a3); }
#define ACC16 ACC4(0)ACC4(1)ACC4(2)ACC4(3)ACC4(4)ACC4(5)ACC4(6)ACC4(7) \
              ACC4(8)ACC4(9)ACC4(10)ACC4(11)ACC4(12)ACC4(13)ACC4(14)ACC4(15)

// fp16-pair h × fp32 weights (feed-forward path only): 8 uint4 = 64 values
#define BCH(u) __builtin_bit_cast(half2_t, u)
#define FMX(q, wa, wb) { \
    half2_t p0=BCH(q.x), p1=BCH(q.y), p2=BCH(q.z), p3=BCH(q.w); \
    a0 = fmaf((float)p0.x, wa.x, a0); a1 = fmaf((float)p0.y, wa.y, a1); \
    a2 = fmaf((float)p1.x, wa.z, a2); a3 = fmaf((float)p1.y, wa.w, a3); \
    a0 = fmaf((float)p2.x, wb.x, a0); a1 = fmaf((float)p2.y, wb.y, a1); \
    a2 = fmaf((float)p3.x, wb.z, a2); a3 = fmaf((float)p3.y, wb.w, a3); }
#define DOT64H(hsrc) \
    uint4 q0=hsrc[0],q1=hsrc[1],q2=hsrc[2],q3=hsrc[3], \
          q4=hsrc[4],q5=hsrc[5],q6=hsrc[6],q7=hsrc[7]; \
    FMX(q0,w0,w1) FMX(q1,w2,w3) FMX(q2,w4,w5) FMX(q3,w6,w7) \
    FMX(q4,w8,w9) FMX(q5,w10,w11) FMX(q6,w12,w13) FMX(q7,w14,w15)

// ---------------- kernel 1: embedding gather + layer-1 input GEMM.
// waves_per_eu(1,2): 256-VGPR budget so the 8x8 fp32 acc tile + prefetch
// regs (~150 VGPR) stay in arch VGPRs (suspected R14-era spill at default
// occupancy targeting). Both K-chunks' global loads prefetched up front.
__global__ __launch_bounds__(256)
__attribute__((amdgpu_waves_per_eu(1, 2)))
void k_embed_pre1(
    const int* __restrict__ x, const float* __restrict__ emb,
    const float* __restrict__ Wih1, const float* __restrict__ bih1,
    const float* __restrict__ bhh1, float* __restrict__ pre1)
{
    __shared__ float sA[32][128];
    __shared__ float sW[32][132];
    __shared__ int stok[128];
    const int tid = threadIdx.x;
    const int base = blockIdx.x * 128;
    const int tx = tid & 15, ty = tid >> 4;
    const int ox = tx * 8, py = ty * 8;
    const int pl = tid & 127, half = tid >> 7;
    if (tid < 128) stok[tid] = x[base + tid];
    float acc[8][8];
#pragma unroll
    for (int p = 0; p < 8; ++p)
#pragma unroll
        for (int o = 0; o < 8; ++o) acc[p][o] = 0.f;
    __syncthreads();
    // prefetch BOTH K-chunks (K=64): 8 W float4 + 8 emb float4 per thread
    const float4* ws = (const float4*)(Wih1 + (size_t)pl * EMB + half * 16);
    const float4* as = (const float4*)(emb + (size_t)stok[pl] * EMB + half * 16);
    float4 qw[2][4], qe[2][4];
#pragma unroll
    for (int kc = 0; kc < 2; ++kc)
#pragma unroll
        for (int k = 0; k < 4; ++k) {
            qw[kc][k] = ws[kc * 8 + k];   // +32 floats = +8 float4 per kc
            qe[kc][k] = as[kc * 8 + k];
        }
    for (int kc = 0; kc < 2; ++kc) {
        {
            const int jb = half * 16;
#pragma unroll
            for (int k = 0; k < 4; ++k) {
                float4 q = qw[kc][k], e = qe[kc][k];
                sW[jb + 4*k + 0][pl] = q.x; sW[jb + 4*k + 1][pl] = q.y;
                sW[jb + 4*k + 2][pl] = q.z; sW[jb + 4*k + 3][pl] = q.w;
                sA[jb + 4*k + 0][pl] = e.x; sA[jb + 4*k + 1][pl] = e.y;
                sA[jb + 4*k + 2][pl] = e.z; sA[jb + 4*k + 3][pl] = e.w;
            }
        }
        __syncthreads();
#pragma unroll 4
        for (int j = 0; j < 32; ++j) {
            float4 a0 = *(const float4*)&sA[j][py];
            float4 a1 = *(const float4*)&sA[j][py + 4];
            float4 b0 = *(const float4*)&sW[j][ox];
            float4 b1 = *(const float4*)&sW[j][ox + 4];
            float av[8] = {a0.x,a0.y,a0.z,a0.w,a1.x,a1.y,a1.z,a1.w};
            float bv[8] = {b0.x,b0.y,b0.z,b0.w,b1.x,b1.y,b1.z,b1.w};
#pragma unroll
            for (int p = 0; p < 8; ++p)
#pragma unroll
                for (int o = 0; o < 8; ++o)
                    acc[p][o] = fmaf(av[p], bv[o], acc[p][o]);
        }
        __syncthreads();
    }
    float bo[8];
#pragma unroll
    for (int o = 0; o < 8; ++o) bo[o] = bih1[ox + o] + bhh1[ox + o];
#pragma unroll
    for (int p = 0; p < 8; ++p) {
        float* cp = pre1 + (size_t)(base + py + p) * HID + ox;
        *(float4*)cp       = make_float4(acc[p][0]+bo[0], acc[p][1]+bo[1], acc[p][2]+bo[2], acc[p][3]+bo[3]);
        *(float4*)(cp + 4) = make_float4(acc[p][4]+bo[4], acc[p][5]+bo[5], acc[p][6]+bo[6], acc[p][7]+bo[7]);
    }
}

// block-wide sum for 768 threads (12 waves); pass 0 from non-contributing lanes
__device__ inline float bsum768(float v, volatile float* sc, int tid) {
#pragma unroll
    for (int off = 32; off > 0; off >>= 1) v += __shfl_down(v, off, 64);
    __syncthreads();
    if ((tid & 63) == 0) sc[tid >> 6] = v;
    __syncthreads();
    float s = 0.f;
#pragma unroll
    for (int k = 0; k < 12; ++k) s += sc[k];
    return s;
}

// ---------------- kernel 2: FUSED two-layer recurrence + LN/proj/LN epilogue.
// R12 EXACT (best measured: 484 µs, absmax 0.0078). 768 thr, 12 waves,
// 1-step skew, 2-way K-split with sp LDS combine (R14 proved shfl-combine
// is NOT cheaper — __shfl is ds_bpermute on the same LDS pipe).
__global__ __launch_bounds__(768)
__attribute__((amdgpu_waves_per_eu(1, 3)))
void k_rnn_fused(
    const float* __restrict__ pre1, const float* __restrict__ Whh1,
    const float* __restrict__ Wih2, const float* __restrict__ bih2,
    const float* __restrict__ bhh2, const float* __restrict__ Whh2,
    const float* __restrict__ ln_g, const float* __restrict__ ln_b,
    const float* __restrict__ projW, const float* __restrict__ proj_b,
    const float* __restrict__ on_g, const float* __restrict__ on_b,
    float* __restrict__ out)
{
    __shared__ __align__(16) float    h1b[2][HID];   // fp32 h1 (recurrent read, A)
    __shared__ __align__(16) _Float16 h1h[2][HID];   // fp16 h1 copy (B only)
    __shared__ __align__(16) float    h2b[2][HID];   // fp32 h2 (recurrent read, C)
    __shared__ __align__(16) float sp[3][2][HID];    // per-group K-split partials
    __shared__ __align__(16) float spre[CH * HID];   // staged pre1 rows (16 KB)
    __shared__ float sfin[HID];
    __shared__ float sc[12];
    const int b    = blockIdx.x;
    const int tid  = threadIdx.x;
    const int g    = tid >> 8;        // 0=A,1=B,2=C (wave-uniform)
    const int gt   = tid & 255;
    const int i    = gt & 127;
    const int half = gt >> 7;
    const float* wbase = (g == 0) ? Whh1 : ((g == 1) ? Wih2 : Whh2);
    const float4* wr = reinterpret_cast<const float4*>(wbase + (size_t)i * HID + half * 64);
    W16LOAD; W16PIN;
    const float bias2 = (g == 1) ? (bih2[i] + bhh2[i]) : 0.f;
    if (tid < 128) {
        h1b[0][tid] = 0.f; h1h[0][tid] = (_Float16)0.f; h2b[0][tid] = 0.f;
    }
    const float4* gsrc = reinterpret_cast<const float4*>(pre1 + (size_t)b * 512 * HID);
    float4*       spv  = reinterpret_cast<float4*>(spre);
    __syncthreads();
    for (int c = 0; c < 512 / CH; ++c) {
        // stage CH pre1 rows: 1024 float4, threads 0..511 take 2 each
        if (tid < 512) {
            float4 r0 = gsrc[c * 1024 + tid];
            float4 r1 = gsrc[c * 1024 + tid + 512];
            spv[tid]       = r0;
            spv[tid + 512] = r1;
        }
        __syncthreads();
        for (int s = 0; s < CH; ++s) {
            const int t = c * CH + s;
            if (g == 1) {               // fp16 h1 read (feed-forward path)
                const uint4* hsrc = reinterpret_cast<const uint4*>(h1h[t & 1] + half * 64);
                float a0 = 0, a1 = 0, a2 = 0, a3 = 0;
                DOT64H(hsrc);
                sp[1][half][i] = (a0 + a1) + (a2 + a3);
            } else {                    // fp32 recurrent reads
                const float* hsel = (g == 0) ? h1b[t & 1] : h2b[t & 1];
                const float4* hp = reinterpret_cast<const float4*>(hsel + half * 64);
                float a0 = 0, a1 = 0, a2 = 0, a3 = 0;
                ACC16;
                sp[g][half][i] = (a0 + a1) + (a2 + a3);
            }
            __syncthreads();
            if (tid < 128) {               // waves 0-1: publish h1_t (both formats)
                float hn = fast_tanh(spre[s * HID + i] + sp[0][0][i] + sp[0][1][i]);
                h1b[(t + 1) & 1][i] = hn;
                h1h[(t + 1) & 1][i] = (_Float16)hn;
            } else if (g == 1 && gt < 128) {  // waves 4-5: publish h2_{t-1}
                float v = bias2 + sp[1][0][i] + sp[1][1][i] + sp[2][0][i] + sp[2][1][i];
                h2b[(t + 1) & 1][i] = (t > 0) ? fast_tanh(v) : 0.f;
            }
            __syncthreads();
        }
    }
    // drain: h2_511 = tanh(bias2 + Wih2@h1_511 + Whh2@h2_510)
    if (g == 1) {
        const uint4* hsrc = reinterpret_cast<const uint4*>(h1h[0] + half * 64);
        float a0 = 0, a1 = 0, a2 = 0, a3 = 0;
        DOT64H(hsrc);
        sp[1][half][i] = (a0 + a1) + (a2 + a3);
    } else if (g == 2) {
        const float4* hp = reinterpret_cast<const float4*>(h2b[0] + half * 64);
        float a0 = 0, a1 = 0, a2 = 0, a3 = 0;
        ACC16;
        sp[2][half][i] = (a0 + a1) + (a2 + a3);
    }
    __syncthreads();
    if (g == 1 && gt < 128)
        sfin[i] = fast_tanh(bias2 + sp[1][0][i] + sp[1][1][i] + sp[2][0][i] + sp[2][1][i]);
    __syncthreads();
    // ---- epilogue: LN -> proj+tanh -> LN (values on tid<128; all barrier)
    float hn = (tid < 128) ? sfin[i] : 0.f;
    float s1 = bsum768(hn, sc, tid);
    float s2 = bsum768(hn * hn, sc, tid);
    float mu = s1 * (1.f / 128.f);
    float var = s2 * (1.f / 128.f) - mu * mu;
    __syncthreads();
    if (tid < 128) spre[i] = (hn - mu) * rsqrtf(var + 1e-5f) * ln_g[i] + ln_b[i];
    __syncthreads();
    float pv = 0.f;
    if (tid < 128) {
        float a0 = proj_b[i], a1 = 0, a2 = 0, a3 = 0;
        const float4* hp = reinterpret_cast<const float4*>(spre);
        const float4* pr = reinterpret_cast<const float4*>(projW + (size_t)i * HID);
#pragma unroll
        for (int k = 0; k < HID / 4; ++k) {
            float4 u = pr[k];
            float4 hv = hp[k];
            a0 = fmaf(hv.x, u.x, a0); a1 = fmaf(hv.y, u.y, a1);
            a2 = fmaf(hv.z, u.z, a2); a3 = fmaf(hv.w, u.w, a3);
        }
        pv = tanhf((a0 + a1) + (a2 + a3));
    }
    float t1 = bsum768(pv, sc, tid);
    float t2 = bsum768(pv * pv, sc, tid);
    float mu2 = t1 * (1.f / 128.f);
    float var2 = t2 * (1.f / 128.f) - mu2 * mu2;
    if (tid < 128)
        out[(size_t)b * HID + i] = (pv - mu2) * rsqrtf(var2 + 1e-5f) * on_g[i] + on_b[i];
}

extern "C" void kernel_launch(void* const* d_in, const int* in_sizes, int n_in,
                              void* d_out, int out_size, void* d_ws, size_t ws_size,
                              hipStream_t stream)
{
    const int*   x     = (const int*)  d_in[0];
    const float* emb   = (const float*)d_in[1];
    const float* Wih1  = (const float*)d_in[2];
    const float* bih1  = (const float*)d_in[3];
    const float* Whh1  = (const float*)d_in[4];
    const float* bhh1  = (const float*)d_in[5];
    const float* Wih2  = (const float*)d_in[6];
    const float* bih2  = (const float*)d_in[7];
    const float* Whh2  = (const float*)d_in[8];
    const float* bhh2  = (const float*)d_in[9];
    const float* ln_g  = (const float*)d_in[10];
    const float* ln_b  = (const float*)d_in[11];
    const float* projW = (const float*)d_in[12];
    const float* projb = (const float*)d_in[13];
    const float* on_g  = (const float*)d_in[14];
    const float* on_b  = (const float*)d_in[15];

    float* pre1 = (float*)d_ws;   // 64 MiB fp32

    k_embed_pre1<<<BT / 128, 256, 0, stream>>>(x, emb, Wih1, bih1, bhh1, pre1);
    k_rnn_fused<<<256, 768, 0, stream>>>(pre1, Whh1, Wih2, bih2, bhh2, Whh2,
                                         ln_g, ln_b, projW, projb, on_g, on_b,
                                         (float*)d_out);
}

// Round 16
// 470.050 us; speedup vs baseline: 3.8089x; 1.2074x over previous
//
#include <hip/hip_runtime.h>

#define BT (256*512)   // 131072 positions
#define HID 128
#define EMB 64
#define CH 32          // scan chunk: steps staged per LDS refill

typedef _Float16 half2_t __attribute__((ext_vector_type(2)));

__device__ inline float fast_tanh(float x) {   // 1 - 2/(exp(2x)+1), ~1e-6 abs err
    float e = __expf(2.f * x);
    return 1.f - __fdividef(2.f, e + 1.f);
}

// pin a float4 in VGPRs (compiler cannot rematerialize past this) — R6 recipe
#define OPQ(v) asm volatile("" : "+v"(v.x), "+v"(v.y), "+v"(v.z), "+v"(v.w))
#define W16PIN \
    OPQ(w0);OPQ(w1);OPQ(w2);OPQ(w3);OPQ(w4);OPQ(w5);OPQ(w6);OPQ(w7); \
    OPQ(w8);OPQ(w9);OPQ(w10);OPQ(w11);OPQ(w12);OPQ(w13);OPQ(w14);OPQ(w15);
// dual-row load: w0..w7 = row r0 K-slice, w8..w15 = row r0+64 same K-slice
#define WDUALLOAD \
    float4 w0=wr0[0],w1=wr0[1],w2=wr0[2],w3=wr0[3],w4=wr0[4],w5=wr0[5],w6=wr0[6],w7=wr0[7], \
           w8=wr1[0],w9=wr1[1],w10=wr1[2],w11=wr1[3],w12=wr1[4],w13=wr1[5],w14=wr1[6],w15=wr1[7];

// fp32 dual-row dot over a 32-value h slice: 8 b128 reads shared by 2 rows
#define DACC(n, m) { float4 hv = hp[n]; \
    a0=fmaf(hv.x,w##n.x,a0); a1=fmaf(hv.y,w##n.y,a1); \
    a2=fmaf(hv.z,w##n.z,a2); a3=fmaf(hv.w,w##n.w,a3); \
    c0=fmaf(hv.x,w##m.x,c0); c1=fmaf(hv.y,w##m.y,c1); \
    c2=fmaf(hv.z,w##m.z,c2); c3=fmaf(hv.w,w##m.w,c3); }
#define DACC8 DACC(0,8) DACC(1,9) DACC(2,10) DACC(3,11) \
              DACC(4,12) DACC(5,13) DACC(6,14) DACC(7,15)

// fp16 dual-row dot over a 32-value h slice: 4 uint4 reads shared by 2 rows
#define BCH(u) __builtin_bit_cast(half2_t, u)
#define FMX2(qq, wa, wb, wc, wd) { \
    half2_t p0=BCH(qq.x), p1=BCH(qq.y), p2=BCH(qq.z), p3=BCH(qq.w); \
    float f0=(float)p0.x, f1=(float)p0.y, f2=(float)p1.x, f3=(float)p1.y, \
          f4=(float)p2.x, f5=(float)p2.y, f6=(float)p3.x, f7=(float)p3.y; \
    a0=fmaf(f0,wa.x,a0); a1=fmaf(f1,wa.y,a1); a2=fmaf(f2,wa.z,a2); a3=fmaf(f3,wa.w,a3); \
    a0=fmaf(f4,wb.x,a0); a1=fmaf(f5,wb.y,a1); a2=fmaf(f6,wb.z,a2); a3=fmaf(f7,wb.w,a3); \
    c0=fmaf(f0,wc.x,c0); c1=fmaf(f1,wc.y,c1); c2=fmaf(f2,wc.z,c2); c3=fmaf(f3,wc.w,c3); \
    c0=fmaf(f4,wd.x,c0); c1=fmaf(f5,wd.y,c1); c2=fmaf(f6,wd.z,c2); c3=fmaf(f7,wd.w,c3); }
#define DOT32H2(hsrc) \
    { uint4 q0h=hsrc[0],q1h=hsrc[1],q2h=hsrc[2],q3h=hsrc[3]; \
      FMX2(q0h,w0,w1,w8,w9) FMX2(q1h,w2,w3,w10,w11) \
      FMX2(q2h,w4,w5,w12,w13) FMX2(q3h,w6,w7,w14,w15) }

// ---------------- kernel 1: embedding gather + layer-1 input GEMM (R15 form)
__global__ __launch_bounds__(256)
__attribute__((amdgpu_waves_per_eu(1, 2)))
void k_embed_pre1(
    const int* __restrict__ x, const float* __restrict__ emb,
    const float* __restrict__ Wih1, const float* __restrict__ bih1,
    const float* __restrict__ bhh1, float* __restrict__ pre1)
{
    __shared__ float sA[32][128];
    __shared__ float sW[32][132];
    __shared__ int stok[128];
    const int tid = threadIdx.x;
    const int base = blockIdx.x * 128;
    const int tx = tid & 15, ty = tid >> 4;
    const int ox = tx * 8, py = ty * 8;
    const int pl = tid & 127, half = tid >> 7;
    if (tid < 128) stok[tid] = x[base + tid];
    float acc[8][8];
#pragma unroll
    for (int p = 0; p < 8; ++p)
#pragma unroll
        for (int o = 0; o < 8; ++o) acc[p][o] = 0.f;
    __syncthreads();
    const float4* ws = (const float4*)(Wih1 + (size_t)pl * EMB + half * 16);
    const float4* as = (const float4*)(emb + (size_t)stok[pl] * EMB + half * 16);
    float4 qw[2][4], qe[2][4];
#pragma unroll
    for (int kc = 0; kc < 2; ++kc)
#pragma unroll
        for (int k = 0; k < 4; ++k) {
            qw[kc][k] = ws[kc * 8 + k];
            qe[kc][k] = as[kc * 8 + k];
        }
    for (int kc = 0; kc < 2; ++kc) {
        {
            const int jb = half * 16;
#pragma unroll
            for (int k = 0; k < 4; ++k) {
                float4 q = qw[kc][k], e = qe[kc][k];
                sW[jb + 4*k + 0][pl] = q.x; sW[jb + 4*k + 1][pl] = q.y;
                sW[jb + 4*k + 2][pl] = q.z; sW[jb + 4*k + 3][pl] = q.w;
                sA[jb + 4*k + 0][pl] = e.x; sA[jb + 4*k + 1][pl] = e.y;
                sA[jb + 4*k + 2][pl] = e.z; sA[jb + 4*k + 3][pl] = e.w;
            }
        }
        __syncthreads();
#pragma unroll 4
        for (int j = 0; j < 32; ++j) {
            float4 a0 = *(const float4*)&sA[j][py];
            float4 a1 = *(const float4*)&sA[j][py + 4];
            float4 b0 = *(const float4*)&sW[j][ox];
            float4 b1 = *(const float4*)&sW[j][ox + 4];
            float av[8] = {a0.x,a0.y,a0.z,a0.w,a1.x,a1.y,a1.z,a1.w};
            float bv[8] = {b0.x,b0.y,b0.z,b0.w,b1.x,b1.y,b1.z,b1.w};
#pragma unroll
            for (int p = 0; p < 8; ++p)
#pragma unroll
                for (int o = 0; o < 8; ++o)
                    acc[p][o] = fmaf(av[p], bv[o], acc[p][o]);
        }
        __syncthreads();
    }
    float bo[8];
#pragma unroll
    for (int o = 0; o < 8; ++o) bo[o] = bih1[ox + o] + bhh1[ox + o];
#pragma unroll
    for (int p = 0; p < 8; ++p) {
        float* cp = pre1 + (size_t)(base + py + p) * HID + ox;
        *(float4*)cp       = make_float4(acc[p][0]+bo[0], acc[p][1]+bo[1], acc[p][2]+bo[2], acc[p][3]+bo[3]);
        *(float4*)(cp + 4) = make_float4(acc[p][4]+bo[4], acc[p][5]+bo[5], acc[p][6]+bo[6], acc[p][7]+bo[7]);
    }
}

// block-wide sum for 768 threads (12 waves); pass 0 from non-contributing lanes
__device__ inline float bsum768(float v, volatile float* sc, int tid) {
#pragma unroll
    for (int off = 32; off > 0; off >>= 1) v += __shfl_down(v, off, 64);
    __syncthreads();
    if ((tid & 63) == 0) sc[tid >> 6] = v;
    __syncthreads();
    float s = 0.f;
#pragma unroll
    for (int k = 0; k < 12; ++k) s += sc[k];
    return s;
}

// ---------------- kernel 2: FUSED two-layer recurrence + LN/proj/LN epilogue.
// R12 structure, but 4-way K-split × 2 rows/thread: thread (q=gt>>6, r0=gt&63)
// handles rows {r0, r0+64}, K-slice [32q,32q+32). One h-read feeds TWO dots,
// halving the dominant LDS-slot term (R15 slot model: 192 -> ~136 slots/step).
// q is wave-uniform -> broadcast reads stay conflict-free. 64 pinned
// floats/thread = R12's proven-safe budget.
__global__ __launch_bounds__(768)
__attribute__((amdgpu_waves_per_eu(1, 3)))
void k_rnn_fused(
    const float* __restrict__ pre1, const float* __restrict__ Whh1,
    const float* __restrict__ Wih2, const float* __restrict__ bih2,
    const float* __restrict__ bhh2, const float* __restrict__ Whh2,
    const float* __restrict__ ln_g, const float* __restrict__ ln_b,
    const float* __restrict__ projW, const float* __restrict__ proj_b,
    const float* __restrict__ on_g, const float* __restrict__ on_b,
    float* __restrict__ out)
{
    __shared__ __align__(16) float    h1b[2][HID];   // fp32 h1 (recurrent, A)
    __shared__ __align__(16) _Float16 h1h[2][HID];   // fp16 h1 copy (B, FF path)
    __shared__ __align__(16) float    h2b[2][HID];   // fp32 h2 (recurrent, C)
    __shared__ __align__(16) float sp[3][4][HID];    // 4-way K-split partials
    __shared__ __align__(16) float spre[CH * HID];   // staged pre1 rows (16 KB)
    __shared__ float sfin[HID];
    __shared__ float sc[12];
    const int b   = blockIdx.x;
    const int tid = threadIdx.x;
    const int g   = tid >> 8;         // 0=A,1=B,2=C
    const int gt  = tid & 255;
    const int q   = gt >> 6;          // K-quarter (wave-uniform)
    const int r0  = gt & 63;          // owns rows r0 and r0+64
    const int i   = gt & 127;         // publisher index
    const float* wbase = (g == 0) ? Whh1 : ((g == 1) ? Wih2 : Whh2);
    const float4* wr0 = reinterpret_cast<const float4*>(wbase + (size_t)r0 * HID + q * 32);
    const float4* wr1 = reinterpret_cast<const float4*>(wbase + (size_t)(r0 + 64) * HID + q * 32);
    WDUALLOAD; W16PIN;
    const float bias2 = (g == 1) ? (bih2[i] + bhh2[i]) : 0.f;
    if (tid < 128) {
        h1b[0][tid] = 0.f; h1h[0][tid] = (_Float16)0.f; h2b[0][tid] = 0.f;
    }
    const float4* gsrc = reinterpret_cast<const float4*>(pre1 + (size_t)b * 512 * HID);
    float4*       spv  = reinterpret_cast<float4*>(spre);
    __syncthreads();
    for (int c = 0; c < 512 / CH; ++c) {
        // stage CH pre1 rows: 1024 float4, threads 0..511 take 2 each
        if (tid < 512) {
            float4 rr0 = gsrc[c * 1024 + tid];
            float4 rr1 = gsrc[c * 1024 + tid + 512];
            spv[tid]       = rr0;
            spv[tid + 512] = rr1;
        }
        __syncthreads();
        for (int s = 0; s < CH; ++s) {
            const int t = c * CH + s;
            float a0 = 0, a1 = 0, a2 = 0, a3 = 0;
            float c0 = 0, c1 = 0, c2 = 0, c3 = 0;
            if (g == 1) {               // fp16 h1 read (feed-forward path)
                const uint4* hsrc = reinterpret_cast<const uint4*>(h1h[t & 1] + q * 32);
                DOT32H2(hsrc);
            } else {                    // fp32 recurrent reads
                const float* hsel = (g == 0) ? h1b[t & 1] : h2b[t & 1];
                const float4* hp = reinterpret_cast<const float4*>(hsel + q * 32);
                DACC8;
            }
            sp[g][q][r0]      = (a0 + a1) + (a2 + a3);
            sp[g][q][r0 + 64] = (c0 + c1) + (c2 + c3);
            __syncthreads();
            if (tid < 128) {               // waves 0-1: publish h1_t (both formats)
                float hn = fast_tanh(spre[s * HID + i] +
                    ((sp[0][0][i] + sp[0][1][i]) + (sp[0][2][i] + sp[0][3][i])));
                h1b[(t + 1) & 1][i] = hn;
                h1h[(t + 1) & 1][i] = (_Float16)hn;
            } else if (g == 1 && gt < 128) {  // waves 4-5: publish h2_{t-1}
                float v = bias2 +
                    ((sp[1][0][i] + sp[1][1][i]) + (sp[1][2][i] + sp[1][3][i])) +
                    ((sp[2][0][i] + sp[2][1][i]) + (sp[2][2][i] + sp[2][3][i]));
                h2b[(t + 1) & 1][i] = (t > 0) ? fast_tanh(v) : 0.f;
            }
            __syncthreads();
        }
    }
    // drain: h2_511 = tanh(bias2 + Wih2@h1_511 + Whh2@h2_510)
    {
        float a0 = 0, a1 = 0, a2 = 0, a3 = 0;
        float c0 = 0, c1 = 0, c2 = 0, c3 = 0;
        if (g == 1) {
            const uint4* hsrc = reinterpret_cast<const uint4*>(h1h[0] + q * 32);
            DOT32H2(hsrc);
            sp[1][q][r0]      = (a0 + a1) + (a2 + a3);
            sp[1][q][r0 + 64] = (c0 + c1) + (c2 + c3);
        } else if (g == 2) {
            const float4* hp = reinterpret_cast<const float4*>(h2b[0] + q * 32);
            DACC8;
            sp[2][q][r0]      = (a0 + a1) + (a2 + a3);
            sp[2][q][r0 + 64] = (c0 + c1) + (c2 + c3);
        }
    }
    __syncthreads();
    if (g == 1 && gt < 128)
        sfin[i] = fast_tanh(bias2 +
            ((sp[1][0][i] + sp[1][1][i]) + (sp[1][2][i] + sp[1][3][i])) +
            ((sp[2][0][i] + sp[2][1][i]) + (sp[2][2][i] + sp[2][3][i])));
    __syncthreads();
    // ---- epilogue: LN -> proj+tanh -> LN (values on tid<128; all barrier)
    float hn = (tid < 128) ? sfin[i] : 0.f;
    float s1 = bsum768(hn, sc, tid);
    float s2 = bsum768(hn * hn, sc, tid);
    float mu = s1 * (1.f / 128.f);
    float var = s2 * (1.f / 128.f) - mu * mu;
    __syncthreads();
    if (tid < 128) spre[i] = (hn - mu) * rsqrtf(var + 1e-5f) * ln_g[i] + ln_b[i];
    __syncthreads();
    float pv = 0.f;
    if (tid < 128) {
        float a0 = proj_b[i], a1 = 0, a2 = 0, a3 = 0;
        const float4* hp = reinterpret_cast<const float4*>(spre);
        const float4* pr = reinterpret_cast<const float4*>(projW + (size_t)i * HID);
#pragma unroll
        for (int k = 0; k < HID / 4; ++k) {
            float4 u = pr[k];
            float4 hv = hp[k];
            a0 = fmaf(hv.x, u.x, a0); a1 = fmaf(hv.y, u.y, a1);
            a2 = fmaf(hv.z, u.z, a2); a3 = fmaf(hv.w, u.w, a3);
        }
        pv = tanhf((a0 + a1) + (a2 + a3));
    }
    float t1 = bsum768(pv, sc, tid);
    float t2 = bsum768(pv * pv, sc, tid);
    float mu2 = t1 * (1.f / 128.f);
    float var2 = t2 * (1.f / 128.f) - mu2 * mu2;
    if (tid < 128)
        out[(size_t)b * HID + i] = (pv - mu2) * rsqrtf(var2 + 1e-5f) * on_g[i] + on_b[i];
}

extern "C" void kernel_launch(void* const* d_in, const int* in_sizes, int n_in,
                              void* d_out, int out_size, void* d_ws, size_t ws_size,
                              hipStream_t stream)
{
    const int*   x     = (const int*)  d_in[0];
    const float* emb   = (const float*)d_in[1];
    const float* Wih1  = (const float*)d_in[2];
    const float* bih1  = (const float*)d_in[3];
    const float* Whh1  = (const float*)d_in[4];
    const float* bhh1  = (const float*)d_in[5];
    const float* Wih2  = (const float*)d_in[6];
    const float* bih2  = (const float*)d_in[7];
    const float* Whh2  = (const float*)d_in[8];
    const float* bhh2  = (const float*)d_in[9];
    const float* ln_g  = (const float*)d_in[10];
    const float* ln_b  = (const float*)d_in[11];
    const float* projW = (const float*)d_in[12];
    const float* projb = (const float*)d_in[13];
    const float* on_g  = (const float*)d_in[14];
    const float* on_b  = (const float*)d_in[15];

    float* pre1 = (float*)d_ws;   // 64 MiB fp32

    k_embed_pre1<<<BT / 128, 256, 0, stream>>>(x, emb, Wih1, bih1, bhh1, pre1);
    k_rnn_fused<<<256, 768, 0, stream>>>(pre1, Whh1, Wih2, bih2, bhh2, Whh2,
                                         ln_g, ln_b, projW, projb, on_g, on_b,
                                         (float*)d_out);
}

// Round 18
// 469.613 us; speedup vs baseline: 3.8125x; 1.0009x over previous
//
#include <hip/hip_runtime.h>

#define BT (256*512)   // 131072 positions
#define HID 128
#define EMB 64
#define CH 32          // scan chunk: steps staged per LDS refill

typedef _Float16 half2_t __attribute__((ext_vector_type(2)));

__device__ inline float fast_tanh(float x) {   // 1 - 2/(exp(2x)+1), ~1e-6 abs err
    float e = __expf(2.f * x);
    return 1.f - __fdividef(2.f, e + 1.f);
}

// pin a float4 in VGPRs (compiler cannot rematerialize past this) — R6 recipe
#define OPQ(v) asm volatile("" : "+v"(v.x), "+v"(v.y), "+v"(v.z), "+v"(v.w))
#define W16PIN \
    OPQ(w0);OPQ(w1);OPQ(w2);OPQ(w3);OPQ(w4);OPQ(w5);OPQ(w6);OPQ(w7); \
    OPQ(w8);OPQ(w9);OPQ(w10);OPQ(w11);OPQ(w12);OPQ(w13);OPQ(w14);OPQ(w15);
// dual-row load: w0..w7 = row r0 K-slice, w8..w15 = row r0+64 same K-slice
#define WDUALLOAD \
    float4 w0=wr0[0],w1=wr0[1],w2=wr0[2],w3=wr0[3],w4=wr0[4],w5=wr0[5],w6=wr0[6],w7=wr0[7], \
           w8=wr1[0],w9=wr1[1],w10=wr1[2],w11=wr1[3],w12=wr1[4],w13=wr1[5],w14=wr1[6],w15=wr1[7];

// fp32 dual-row dot over a 32-value h slice: 8 b128 reads shared by 2 rows
#define DACC(n, m) { float4 hv = hp[n]; \
    a0=fmaf(hv.x,w##n.x,a0); a1=fmaf(hv.y,w##n.y,a1); \
    a2=fmaf(hv.z,w##n.z,a2); a3=fmaf(hv.w,w##n.w,a3); \
    c0=fmaf(hv.x,w##m.x,c0); c1=fmaf(hv.y,w##m.y,c1); \
    c2=fmaf(hv.z,w##m.z,c2); c3=fmaf(hv.w,w##m.w,c3); }
#define DACC8 DACC(0,8) DACC(1,9) DACC(2,10) DACC(3,11) \
              DACC(4,12) DACC(5,13) DACC(6,14) DACC(7,15)

// fp16 dual-row dot over a 32-value h slice: 4 uint4 reads shared by 2 rows
#define BCH(u) __builtin_bit_cast(half2_t, u)
#define FMX2(qq, wa, wb, wc, wd) { \
    half2_t p0=BCH(qq.x), p1=BCH(qq.y), p2=BCH(qq.z), p3=BCH(qq.w); \
    float f0=(float)p0.x, f1=(float)p0.y, f2=(float)p1.x, f3=(float)p1.y, \
          f4=(float)p2.x, f5=(float)p2.y, f6=(float)p3.x, f7=(float)p3.y; \
    a0=fmaf(f0,wa.x,a0); a1=fmaf(f1,wa.y,a1); a2=fmaf(f2,wa.z,a2); a3=fmaf(f3,wa.w,a3); \
    a0=fmaf(f4,wb.x,a0); a1=fmaf(f5,wb.y,a1); a2=fmaf(f6,wb.z,a2); a3=fmaf(f7,wb.w,a3); \
    c0=fmaf(f0,wc.x,c0); c1=fmaf(f1,wc.y,c1); c2=fmaf(f2,wc.z,c2); c3=fmaf(f3,wc.w,c3); \
    c0=fmaf(f4,wd.x,c0); c1=fmaf(f5,wd.y,c1); c2=fmaf(f6,wd.z,c2); c3=fmaf(f7,wd.w,c3); }
#define DOT32H2(hsrc) \
    { uint4 q0h=hsrc[0],q1h=hsrc[1],q2h=hsrc[2],q3h=hsrc[3]; \
      FMX2(q0h,w0,w1,w8,w9) FMX2(q1h,w2,w3,w10,w11) \
      FMX2(q2h,w4,w5,w12,w13) FMX2(q3h,w6,w7,w14,w15) }

// ---------------- kernel 1: embedding gather + layer-1 input GEMM (R15 form)
__global__ __launch_bounds__(256)
__attribute__((amdgpu_waves_per_eu(1, 2)))
void k_embed_pre1(
    const int* __restrict__ x, const float* __restrict__ emb,
    const float* __restrict__ Wih1, const float* __restrict__ bih1,
    const float* __restrict__ bhh1, float* __restrict__ pre1)
{
    __shared__ float sA[32][128];
    __shared__ float sW[32][132];
    __shared__ int stok[128];
    const int tid = threadIdx.x;
    const int base = blockIdx.x * 128;
    const int tx = tid & 15, ty = tid >> 4;
    const int ox = tx * 8, py = ty * 8;
    const int pl = tid & 127, half = tid >> 7;
    if (tid < 128) stok[tid] = x[base + tid];
    float acc[8][8];
#pragma unroll
    for (int p = 0; p < 8; ++p)
#pragma unroll
        for (int o = 0; o < 8; ++o) acc[p][o] = 0.f;
    __syncthreads();
    const float4* ws = (const float4*)(Wih1 + (size_t)pl * EMB + half * 16);
    const float4* as = (const float4*)(emb + (size_t)stok[pl] * EMB + half * 16);
    float4 qw[2][4], qe[2][4];
#pragma unroll
    for (int kc = 0; kc < 2; ++kc)
#pragma unroll
        for (int k = 0; k < 4; ++k) {
            qw[kc][k] = ws[kc * 8 + k];
            qe[kc][k] = as[kc * 8 + k];
        }
    for (int kc = 0; kc < 2; ++kc) {
        {
            const int jb = half * 16;
#pragma unroll
            for (int k = 0; k < 4; ++k) {
                float4 q = qw[kc][k], e = qe[kc][k];
                sW[jb + 4*k + 0][pl] = q.x; sW[jb + 4*k + 1][pl] = q.y;
                sW[jb + 4*k + 2][pl] = q.z; sW[jb + 4*k + 3][pl] = q.w;
                sA[jb + 4*k + 0][pl] = e.x; sA[jb + 4*k + 1][pl] = e.y;
                sA[jb + 4*k + 2][pl] = e.z; sA[jb + 4*k + 3][pl] = e.w;
            }
        }
        __syncthreads();
#pragma unroll 4
        for (int j = 0; j < 32; ++j) {
            float4 a0 = *(const float4*)&sA[j][py];
            float4 a1 = *(const float4*)&sA[j][py + 4];
            float4 b0 = *(const float4*)&sW[j][ox];
            float4 b1 = *(const float4*)&sW[j][ox + 4];
            float av[8] = {a0.x,a0.y,a0.z,a0.w,a1.x,a1.y,a1.z,a1.w};
            float bv[8] = {b0.x,b0.y,b0.z,b0.w,b1.x,b1.y,b1.z,b1.w};
#pragma unroll
            for (int p = 0; p < 8; ++p)
#pragma unroll
                for (int o = 0; o < 8; ++o)
                    acc[p][o] = fmaf(av[p], bv[o], acc[p][o]);
        }
        __syncthreads();
    }
    float bo[8];
#pragma unroll
    for (int o = 0; o < 8; ++o) bo[o] = bih1[ox + o] + bhh1[ox + o];
#pragma unroll
    for (int p = 0; p < 8; ++p) {
        float* cp = pre1 + (size_t)(base + py + p) * HID + ox;
        *(float4*)cp       = make_float4(acc[p][0]+bo[0], acc[p][1]+bo[1], acc[p][2]+bo[2], acc[p][3]+bo[3]);
        *(float4*)(cp + 4) = make_float4(acc[p][4]+bo[4], acc[p][5]+bo[5], acc[p][6]+bo[6], acc[p][7]+bo[7]);
    }
}

// block-wide sum for 768 threads (12 waves); pass 0 from non-contributing lanes
__device__ inline float bsum768(float v, volatile float* sc, int tid) {
#pragma unroll
    for (int off = 32; off > 0; off >>= 1) v += __shfl_down(v, off, 64);
    __syncthreads();
    if ((tid & 63) == 0) sc[tid >> 6] = v;
    __syncthreads();
    float s = 0.f;
#pragma unroll
    for (int k = 0; k < 12; ++k) s += sc[k];
    return s;
}

// ---------------- kernel 2: FUSED two-layer recurrence + LN/proj/LN epilogue.
// R16 EXACT (374.7 µs measured): 4-way K-split x 2 rows/thread; one h-read
// feeds two dots. q wave-uniform -> broadcast reads conflict-free. 64 pinned
// floats/thread (proven-safe budget).
__global__ __launch_bounds__(768)
__attribute__((amdgpu_waves_per_eu(1, 3)))
void k_rnn_fused(
    const float* __restrict__ pre1, const float* __restrict__ Whh1,
    const float* __restrict__ Wih2, const float* __restrict__ bih2,
    const float* __restrict__ bhh2, const float* __restrict__ Whh2,
    const float* __restrict__ ln_g, const float* __restrict__ ln_b,
    const float* __restrict__ projW, const float* __restrict__ proj_b,
    const float* __restrict__ on_g, const float* __restrict__ on_b,
    float* __restrict__ out)
{
    __shared__ __align__(16) float    h1b[2][HID];   // fp32 h1 (recurrent, A)
    __shared__ __align__(16) _Float16 h1h[2][HID];   // fp16 h1 copy (B, FF path)
    __shared__ __align__(16) float    h2b[2][HID];   // fp32 h2 (recurrent, C)
    __shared__ __align__(16) float sp[3][4][HID];    // 4-way K-split partials
    __shared__ __align__(16) float spre[CH * HID];   // staged pre1 rows (16 KB)
    __shared__ float sfin[HID];
    __shared__ float sc[12];
    const int b   = blockIdx.x;
    const int tid = threadIdx.x;
    const int g   = tid >> 8;         // 0=A,1=B,2=C
    const int gt  = tid & 255;
    const int q   = gt >> 6;          // K-quarter (wave-uniform)
    const int r0  = gt & 63;          // owns rows r0 and r0+64
    const int i   = gt & 127;         // publisher index
    const float* wbase = (g == 0) ? Whh1 : ((g == 1) ? Wih2 : Whh2);
    const float4* wr0 = reinterpret_cast<const float4*>(wbase + (size_t)r0 * HID + q * 32);
    const float4* wr1 = reinterpret_cast<const float4*>(wbase + (size_t)(r0 + 64) * HID + q * 32);
    WDUALLOAD; W16PIN;
    const float bias2 = (g == 1) ? (bih2[i] + bhh2[i]) : 0.f;
    if (tid < 128) {
        h1b[0][tid] = 0.f; h1h[0][tid] = (_Float16)0.f; h2b[0][tid] = 0.f;
    }
    const float4* gsrc = reinterpret_cast<const float4*>(pre1 + (size_t)b * 512 * HID);
    float4*       spv  = reinterpret_cast<float4*>(spre);
    __syncthreads();
    for (int c = 0; c < 512 / CH; ++c) {
        // stage CH pre1 rows: 1024 float4, threads 0..511 take 2 each
        if (tid < 512) {
            float4 rr0 = gsrc[c * 1024 + tid];
            float4 rr1 = gsrc[c * 1024 + tid + 512];
            spv[tid]       = rr0;
            spv[tid + 512] = rr1;
        }
        __syncthreads();
        for (int s = 0; s < CH; ++s) {
            const int t = c * CH + s;
            float a0 = 0, a1 = 0, a2 = 0, a3 = 0;
            float c0 = 0, c1 = 0, c2 = 0, c3 = 0;
            if (g == 1) {               // fp16 h1 read (feed-forward path)
                const uint4* hsrc = reinterpret_cast<const uint4*>(h1h[t & 1] + q * 32);
                DOT32H2(hsrc);
            } else {                    // fp32 recurrent reads
                const float* hsel = (g == 0) ? h1b[t & 1] : h2b[t & 1];
                const float4* hp = reinterpret_cast<const float4*>(hsel + q * 32);
                DACC8;
            }
            sp[g][q][r0]      = (a0 + a1) + (a2 + a3);
            sp[g][q][r0 + 64] = (c0 + c1) + (c2 + c3);
            __syncthreads();
            if (tid < 128) {               // waves 0-1: publish h1_t (both formats)
                float hn = fast_tanh(spre[s * HID + i] +
                    ((sp[0][0][i] + sp[0][1][i]) + (sp[0][2][i] + sp[0][3][i])));
                h1b[(t + 1) & 1][i] = hn;
                h1h[(t + 1) & 1][i] = (_Float16)hn;
            } else if (g == 1 && gt < 128) {  // waves 4-5: publish h2_{t-1}
                float v = bias2 +
                    ((sp[1][0][i] + sp[1][1][i]) + (sp[1][2][i] + sp[1][3][i])) +
                    ((sp[2][0][i] + sp[2][1][i]) + (sp[2][2][i] + sp[2][3][i]));
                h2b[(t + 1) & 1][i] = (t > 0) ? fast_tanh(v) : 0.f;
            }
            __syncthreads();
        }
    }
    // drain: h2_511 = tanh(bias2 + Wih2@h1_511 + Whh2@h2_510)
    {
        float a0 = 0, a1 = 0, a2 = 0, a3 = 0;
        float c0 = 0, c1 = 0, c2 = 0, c3 = 0;
        if (g == 1) {
            const uint4* hsrc = reinterpret_cast<const uint4*>(h1h[0] + q * 32);
            DOT32H2(hsrc);
            sp[1][q][r0]      = (a0 + a1) + (a2 + a3);
            sp[1][q][r0 + 64] = (c0 + c1) + (c2 + c3);
        } else if (g == 2) {
            const float4* hp = reinterpret_cast<const float4*>(h2b[0] + q * 32);
            DACC8;
            sp[2][q][r0]      = (a0 + a1) + (a2 + a3);
            sp[2][q][r0 + 64] = (c0 + c1) + (c2 + c3);
        }
    }
    __syncthreads();
    if (g == 1 && gt < 128)
        sfin[i] = fast_tanh(bias2 +
            ((sp[1][0][i] + sp[1][1][i]) + (sp[1][2][i] + sp[1][3][i])) +
            ((sp[2][0][i] + sp[2][1][i]) + (sp[2][2][i] + sp[2][3][i])));
    __syncthreads();
    // ---- epilogue: LN -> proj+tanh -> LN (values on tid<128; all barrier)
    float hn = (tid < 128) ? sfin[i] : 0.f;
    float s1 = bsum768(hn, sc, tid);
    float s2 = bsum768(hn * hn, sc, tid);
    float mu = s1 * (1.f / 128.f);
    float var = s2 * (1.f / 128.f) - mu * mu;
    __syncthreads();
    if (tid < 128) spre[i] = (hn - mu) * rsqrtf(var + 1e-5f) * ln_g[i] + ln_b[i];
    __syncthreads();
    float pv = 0.f;
    if (tid < 128) {
        float a0 = proj_b[i], a1 = 0, a2 = 0, a3 = 0;
        const float4* hp = reinterpret_cast<const float4*>(spre);
        const float4* pr = reinterpret_cast<const float4*>(projW + (size_t)i * HID);
#pragma unroll
        for (int k = 0; k < HID / 4; ++k) {
            float4 u = pr[k];
            float4 hv = hp[k];
            a0 = fmaf(hv.x, u.x, a0); a1 = fmaf(hv.y, u.y, a1);
            a2 = fmaf(hv.z, u.z, a2); a3 = fmaf(hv.w, u.w, a3);
        }
        pv = tanhf((a0 + a1) + (a2 + a3));
    }
    float t1 = bsum768(pv, sc, tid);
    float t2 = bsum768(pv * pv, sc, tid);
    float mu2 = t1 * (1.f / 128.f);
    float var2 = t2 * (1.f / 128.f) - mu2 * mu2;
    if (tid < 128)
        out[(size_t)b * HID + i] = (pv - mu2) * rsqrtf(var2 + 1e-5f) * on_g[i] + on_b[i];
}

extern "C" void kernel_launch(void* const* d_in, const int* in_sizes, int n_in,
                              void* d_out, int out_size, void* d_ws, size_t ws_size,
                              hipStream_t stream)
{
    const int*   x     = (const int*)  d_in[0];
    const float* emb   = (const float*)d_in[1];
    const float* Wih1  = (const float*)d_in[2];
    const float* bih1  = (const float*)d_in[3];
    const float* Whh1  = (const float*)d_in[4];
    const float* bhh1  = (const float*)d_in[5];
    const float* Wih2  = (const float*)d_in[6];
    const float* bih2  = (const float*)d_in[7];
    const float* Whh2  = (const float*)d_in[8];
    const float* bhh2  = (const float*)d_in[9];
    const float* ln_g  = (const float*)d_in[10];
    const float* ln_b  = (const float*)d_in[11];
    const float* projW = (const float*)d_in[12];
    const float* projb = (const float*)d_in[13];
    const float* on_g  = (const float*)d_in[14];
    const float* on_b  = (const float*)d_in[15];

    float* pre1 = (float*)d_ws;   // 64 MiB fp32

    k_embed_pre1<<<BT / 128, 256, 0, stream>>>(x, emb, Wih1, bih1, bhh1, pre1);
    k_rnn_fused<<<256, 768, 0, stream>>>(pre1, Whh1, Wih2, bih2, bhh2, Whh2,
                                         ln_g, ln_b, projW, projb, on_g, on_b,
                                         (float*)d_out);
}